// Round 10
// baseline (345.371 us; speedup 1.0000x reference)
//
#include <hip/hip_runtime.h>
#include <hip/hip_bf16.h>
#include <math.h>

typedef unsigned short U16;
typedef unsigned int U32;
typedef __attribute__((ext_vector_type(8))) short bf8;        // 8 x bf16 (MFMA A/B frag)
typedef __attribute__((ext_vector_type(4))) float f4;         // MFMA C/D frag
typedef __attribute__((ext_vector_type(4))) unsigned short u16x4;

#define AS1 __attribute__((address_space(1)))
#define AS3 __attribute__((address_space(3)))

// ---- constants ----
#define BSZ   256
#define NTOK  196
#define NQ    49
#define INDIM 384
#define OUTD  512
#define NH    12
#define DV    64
#define DHD   768
#define KVH   1152
#define NPADR 224      // padded token rows (196 real + 28 zero)

__device__ inline U16 f2bf(float f){
    __hip_bfloat16 h = __float2bfloat16(f);
    return *(U16*)&h;
}
__device__ inline f4 f4zero(){ f4 z; z[0]=0.f; z[1]=0.f; z[2]=0.f; z[3]=0.f; return z; }
__device__ inline bf8 bf8zero(){ bf8 v;
#pragma unroll
    for (int j=0;j<8;++j) v[j]=0; return v; }

// ---------------- prep kernels ----------------
// cast x -> x_bf padded [256][224][384] (rows 196..223 = 0)
__global__ void k_cast8p(const float* __restrict__ in, U16* __restrict__ out, int n8){
    int i = blockIdx.x*256 + threadIdx.x;
    if (i >= n8) return;
    int rall = i / 48;         // 48 = 384/8
    int c8   = i - rall*48;
    int b    = rall / NPADR;
    int r    = rall - b*NPADR;
    U16 o[8];
    if (r < NTOK){
        const float* p = in + ((size_t)(b*NTOK + r))*INDIM + c8*8;
#pragma unroll
        for (int j=0;j<8;++j) o[j] = f2bf(p[j]);
    } else {
#pragma unroll
        for (int j=0;j<8;++j) o[j] = 0;
    }
    *(bf8*)(out + (size_t)i*8) = *(const bf8*)o;
}

// subsampled xs cast: [256][49][384]
__global__ void k_castxs(const float* __restrict__ x, U16* __restrict__ out, int n8){
    int i = blockIdx.x*256 + threadIdx.x;
    if (i >= n8) return;
    int row = i / 48;
    int c8  = i - row*48;
    int b   = row / 49;
    int q   = row - b*49;
    int r_  = q / 7, c_ = q - r_*7;
    const float* p = x + ((size_t)(b*NTOK + 28*r_ + 2*c_))*INDIM + c8*8;
    U16 o[8];
#pragma unroll
    for (int j=0;j<8;++j) o[j] = f2bf(p[j]);
    *(bf8*)(out + (size_t)i*8) = *(const bf8*)o;
}

// all three weight casts in one launch
#define W1C (KVH*INDIM/8)            // 55296
#define W2C (INDIM*INDIM/8)          // 18432
#define W3C (OUTD*DHD/8)             // 49152
__global__ void k_castw(const float* __restrict__ w1, const float* __restrict__ w2,
                        const float* __restrict__ w3, U16* __restrict__ o1,
                        U16* __restrict__ o2, U16* __restrict__ o3){
    int i = blockIdx.x*256 + threadIdx.x;
    const float* p; U16* o;
    if (i < W1C){ p = w1 + (size_t)i*8; o = o1 + (size_t)i*8; }
    else if (i < W1C+W2C){ int k=i-W1C; p = w2 + (size_t)k*8; o = o2 + (size_t)k*8; }
    else if (i < W1C+W2C+W3C){ int k=i-W1C-W2C; p = w3 + (size_t)k*8; o = o3 + (size_t)k*8; }
    else return;
    U16 t[8];
#pragma unroll
    for (int j=0;j<8;++j) t[j] = f2bf(p[j]);
    *(bf8*)o = *(const bf8*)t;
}

// bias expand + BN folds, one launch
#define BIAS_N   (NH*NQ*NTOK)        // 115248
#define BIAS_BLK ((BIAS_N+255)/256)  // 451
#define BN_BLK   ((KVH+INDIM+OUTD)/256)  // 8
__global__ void k_misc(const float* __restrict__ ab, const int* __restrict__ idxs, int n_off,
                       const float* __restrict__ g1, const float* __restrict__ b1,
                       const float* __restrict__ m1, const float* __restrict__ v1,
                       const float* __restrict__ g2, const float* __restrict__ b2,
                       const float* __restrict__ m2, const float* __restrict__ v2,
                       const float* __restrict__ g3, const float* __restrict__ b3,
                       const float* __restrict__ m3, const float* __restrict__ v3,
                       float* __restrict__ s1, float* __restrict__ bo1,
                       float* __restrict__ s2, float* __restrict__ bo2,
                       float* __restrict__ s3, float* __restrict__ bo3,
                       float* __restrict__ bias_out){
    int blk = blockIdx.x;
    int tid = threadIdx.x;
    if (blk < BIAS_BLK){
        int i = blk*256 + tid;
        if (i < BIAS_N){
            int h = i / (NQ*NTOK);
            int qk = i - h*(NQ*NTOK);
            bias_out[i] = ab[h*n_off + idxs[qk]];
        }
    } else {
        int i = (blk-BIAS_BLK)*256 + tid;
        const float *g,*b,*m,*v; float *so,*bo; int k;
        if (i < KVH){ g=g1;b=b1;m=m1;v=v1;so=s1;bo=bo1;k=i; }
        else if (i < KVH+INDIM){ g=g2;b=b2;m=m2;v=v2;so=s2;bo=bo2;k=i-KVH; }
        else { g=g3;b=b3;m=m3;v=v3;so=s3;bo=bo3;k=i-KVH-INDIM; }
        float s = g[k] / sqrtf(v[k] + 1e-5f);
        so[k] = s;
        bo[k] = b[k] - m[k]*s;
    }
}

// ---------------- fused kv-GEMM + attention: 1 head/block, 4 blocks/CU ----------------
// GEMM: C[224 rows][96 cols = k(32)|v(64)], BK=32, 12 K-steps, uniform 5 loads/thr/step,
// counted vmcnt(5). LDS = 20480 u16 = 40,960 B exactly -> 4 blocks/CU (16 waves).
//   staging: A0 [0,7168) A1 [7168,14336) B0 [14336,17408) B1 [17408,20480)
//   post-GEMM (aliases dead staging):
//     VL [0,12800):      [nch<=24][64 d][8 nsub] (writes guarded n0<200)
//     KL [12800,19968):  [4 dch][224 n][8 dsub]
//     PV reads VL nch 25..27 (n>=200) overlap KL -> finite garbage x P=0 = 0.
// P never hits LDS: cross-lane __shfl transpose into PV A-frags.
#define KLO 12800
__global__ __launch_bounds__(256,4) void k_fused(
    const U16* __restrict__ xbf, const U16* __restrict__ kvw, const U16* __restrict__ qo_,
    const float* __restrict__ skv, const float* __restrict__ bkv,
    const float* __restrict__ biasf, U16* __restrict__ aout)
{
    __shared__ U16 smem[20480];   // 40,960 B
    const int hw = blockIdx.x;
    const int bh = (hw & 7)*384 + (hw >> 3);   // bijective XCD swizzle (3072 = 8*384)
    const int b = bh / NH, h = bh - b*NH;
    const int tid = threadIdx.x, lane = tid & 63, w = tid >> 6;
    const int wm = w & 1, wn = w >> 1;
    const int l15 = lane & 15, oct = lane >> 4;

    U16* Ab[2] = { smem + 0,     smem + 7168 };
    U16* Bb[2] = { smem + 14336, smem + 17408 };

    // A: 896 chunks (slot = kch*224 + row); waves 0,1 take 4, waves 2,3 take 3
    U32 aoff[4];
#pragma unroll
    for (int c=0;c<3;++c){
        int s = c*256 + tid;
        int ach = s / NPADR, ar = s - ach*NPADR;
        aoff[c] = (U32)(b*NPADR + ar)*INDIM + ach*8;
    }
    {
        int s = 768 + (tid & 127);
        int ach = s / NPADR, ar = s - ach*NPADR;
        aoff[3] = (U32)(b*NPADR + ar)*INDIM + ach*8;
    }
    // B: 384 chunks (slot = kch*96 + row); waves 0,1 take 1, waves 2,3 take 2
    U32 boff[2];
    {
        int s0 = tid;
        int bc0 = s0 / 96, br0 = s0 - bc0*96;
        boff[0] = (U32)(h*96 + br0)*INDIM + bc0*8;
        int s1 = 128 + (tid | 128);            // tid>=128 -> 256..383
        int bc1 = s1 / 96, br1 = s1 - bc1*96;
        boff[1] = (U32)(h*96 + br1)*INDIM + bc1*8;
    }

    f4 acc[7][3];
#pragma unroll
    for (int i=0;i<7;++i)
#pragma unroll
        for (int j=0;j<3;++j) acc[i][j] = f4zero();

#define STAGE(buf, kb) do{ \
    _Pragma("unroll") \
    for (int c=0;c<3;++c) \
        __builtin_amdgcn_global_load_lds((const AS1 U32*)(xbf + aoff[c] + (kb)), \
            (AS3 U32*)(Ab[buf] + (c*256+tid)*8), 16, 0, 0); \
    if (tid < 128) \
        __builtin_amdgcn_global_load_lds((const AS1 U32*)(xbf + aoff[3] + (kb)), \
            (AS3 U32*)(Ab[buf] + (768+tid)*8), 16, 0, 0); \
    __builtin_amdgcn_global_load_lds((const AS1 U32*)(kvw + boff[0] + (kb)), \
        (AS3 U32*)(Bb[buf] + tid*8), 16, 0, 0); \
    if (tid >= 128) \
        __builtin_amdgcn_global_load_lds((const AS1 U32*)(kvw + boff[1] + (kb)), \
            (AS3 U32*)(Bb[buf] + (128+tid)*8), 16, 0, 0); \
}while(0)

    STAGE(0, 0);

#pragma unroll
    for (int kt=0; kt<12; ++kt){
        const int cur = kt & 1;
        if (kt < 11){
            STAGE(cur^1, (kt+1)*32);
            asm volatile("s_waitcnt vmcnt(5)" ::: "memory");   // tile kt landed; kt+1 in flight
        } else {
            asm volatile("s_waitcnt vmcnt(0)" ::: "memory");
        }
        __builtin_amdgcn_sched_barrier(0);
        __builtin_amdgcn_s_barrier();
        __builtin_amdgcn_sched_barrier(0);

        bf8 af[7], bfr[3];
#pragma unroll
        for (int i=0;i<7;++i)
            af[i]  = *(const bf8*)(Ab[cur] + (oct*NPADR + wm*112 + i*16 + l15)*8);
#pragma unroll
        for (int j=0;j<3;++j)
            bfr[j] = *(const bf8*)(Bb[cur] + (oct*96 + wn*48 + j*16 + l15)*8);
        __builtin_amdgcn_s_setprio(1);
#pragma unroll
        for (int i=0;i<7;++i)
#pragma unroll
            for (int j=0;j<3;++j)
                acc[i][j] = __builtin_amdgcn_mfma_f32_16x16x32_bf16(af[i], bfr[j], acc[i][j], 0, 0, 0);
        __builtin_amdgcn_s_setprio(0);
        __builtin_amdgcn_sched_barrier(0);
        __builtin_amdgcn_s_barrier();       // buf `cur` free for next iteration's staging
        __builtin_amdgcn_sched_barrier(0);
    }
#undef STAGE

    // ---- epilogue: BN fold, scatter acc -> VL/KL (alias dead staging) ----
#pragma unroll
    for (int j=0;j<3;++j){
        const int cc = wn*48 + j*16 + l15;     // [0,96)
        const float sc = skv[h*96 + cc];
        const float bi = bkv[h*96 + cc];
#pragma unroll
        for (int i=0;i<7;++i){
            const int n0 = wm*112 + i*16 + oct*4;  // [0,224)
            if (cc < 32){
#pragma unroll
                for (int r=0;r<4;++r)
                    smem[KLO + ((cc>>3)*NPADR + n0 + r)*8 + (cc&7)] = f2bf(acc[i][j][r]*sc + bi);
            } else if (n0 < 200){              // protect KL overlap (nch>=25 unused: P=0)
                const int dv = cc - 32;
                u16x4 pk;
#pragma unroll
                for (int r=0;r<4;++r) pk[r] = f2bf(acc[i][j][r]*sc + bi);
                *(u16x4*)(smem + ((n0>>3)*64 + dv)*8 + (oct&1)*4) = pk;
            }
        }
    }
    __syncthreads();   // K/V visible to all waves

    // ---- attention: 4 waves, each wave 16 q-cols ----
    const int qg = w*16 + l15;
    bf8 qf = bf8zero();
    if (qg < NQ) qf = *(const bf8*)(qo_ + ((size_t)(b*NQ + qg))*INDIM + h*32 + oct*8);

    f4 sacc[14];
#pragma unroll
    for (int mt=0;mt<14;++mt) sacc[mt] = f4zero();
#pragma unroll
    for (int mt=0;mt<14;++mt){
        const bf8 kf = *(const bf8*)(smem + KLO + (oct*NPADR + mt*16 + l15)*8);
        sacc[mt] = __builtin_amdgcn_mfma_f32_16x16x32_bf16(kf, qf, sacc[mt], 0, 0, 0);
    }

    const float scale = 0.17677669529663689f;   // 1/sqrt(32)
    float mx = -1e30f;
#pragma unroll
    for (int mt=0;mt<14;++mt){
        const int n0 = mt*16 + oct*4;
        f4 bi4 = f4zero();
        if (qg < NQ && n0 < NTOK) bi4 = *(const f4*)(biasf + ((size_t)h*NQ + qg)*NTOK + n0);
#pragma unroll
        for (int r=0;r<4;++r){
            float s = (n0 + r < NTOK) ? sacc[mt][r]*scale + bi4[r] : -1e30f;
            sacc[mt][r] = s;
            mx = fmaxf(mx, s);
        }
    }
    mx = fmaxf(mx, __shfl_xor(mx, 16));
    mx = fmaxf(mx, __shfl_xor(mx, 32));

    float sum = 0.f;
#pragma unroll
    for (int mt=0;mt<14;++mt){
#pragma unroll
        for (int r=0;r<4;++r){
            float p = (mt*16 + oct*4 + r < NTOK) ? __expf(sacc[mt][r] - mx) : 0.f;
            sacc[mt][r] = p;
            sum += p;
        }
    }
    sum += __shfl_xor(sum, 16);
    sum += __shfl_xor(sum, 32);
    const float inv = 1.f / sum;

    // pack P -> bf16 pairs (u32); n = mt*16 + oct*4 + {0,1} / {2,3}
    U32 pw0[14], pw1[14];
#pragma unroll
    for (int mt=0;mt<14;++mt){
        pw0[mt] = (U32)f2bf(sacc[mt][0]*inv) | ((U32)f2bf(sacc[mt][1]*inv) << 16);
        pw1[mt] = (U32)f2bf(sacc[mt][2]*inv) | ((U32)f2bf(sacc[mt][3]*inv) << 16);
    }

    // PV: out(q,d) = P(q,n) @ v(n,d); A-frag via cross-lane shfl transpose
    const int src1 = l15 + (oct & 1)*32;   // source lane for j0..3 (oct_s = (oct&1)*2)
    const int src2 = src1 + 16;            // source lane for j4..7
    const bool hiT = (oct >> 1) != 0;      // tile select: mt = 2kt + (oct>>1)
    f4 pacc[4];
#pragma unroll
    for (int dt=0;dt<4;++dt) pacc[dt] = f4zero();
#pragma unroll
    for (int kt=0;kt<7;++kt){
        U32 a0 = __shfl(pw0[2*kt],   src1), a1 = __shfl(pw1[2*kt],   src1);
        U32 c0 = __shfl(pw0[2*kt+1], src1), c1 = __shfl(pw1[2*kt+1], src1);
        U32 b0 = __shfl(pw0[2*kt],   src2), b1 = __shfl(pw1[2*kt],   src2);
        U32 d0 = __shfl(pw0[2*kt+1], src2), d1 = __shfl(pw1[2*kt+1], src2);
        union { U32 u[4]; bf8 v; } pu;
        pu.u[0] = hiT ? c0 : a0;
        pu.u[1] = hiT ? c1 : a1;
        pu.u[2] = hiT ? d0 : b0;
        pu.u[3] = hiT ? d1 : b1;
#pragma unroll
        for (int dt=0;dt<4;++dt){
            const bf8 vf = *(const bf8*)(smem + ((kt*4 + oct)*64 + dt*16 + l15)*8);
            pacc[dt] = __builtin_amdgcn_mfma_f32_16x16x32_bf16(pu.v, vf, pacc[dt], 0, 0, 0);
        }
    }

    // hard_swish, store bf16 (b, q, h*64+d)
#pragma unroll
    for (int dt=0;dt<4;++dt){
#pragma unroll
        for (int r=0;r<4;++r){
            const int qo2 = w*16 + oct*4 + r;
            if (qo2 < NQ){
                const int d = dt*16 + l15;
                float v = pacc[dt][r];
                float tt = fminf(fmaxf(v + 3.f, 0.f), 6.f);
                aout[((size_t)(b*NQ + qo2))*DHD + h*DV + d] = f2bf(v * tt * (1.f/6.f));
            }
        }
    }
}

// ---------------- q GEMM 128x128x64 (12544 x 384 x 384), bf16 out ----------------
__global__ __launch_bounds__(256,2) void k_qgemm(
    const U16* __restrict__ A, const U16* __restrict__ Bw,
    const float* __restrict__ s_arr, const float* __restrict__ b_arr,
    U16* __restrict__ o16)
{
    __shared__ U16 smem[32768];
    U16* Ab[2] = { smem,          smem + 8192 };
    U16* Bb[2] = { smem + 16384,  smem + 24576 };
    const int gn0 = blockIdx.x * 128;
    const int gm0 = blockIdx.y * 128;
    const int tid  = threadIdx.x;
    const int lane = tid & 63;
    const int w    = tid >> 6;
    const int wm   = w >> 1, wn = w & 1;
    const int l15  = lane & 15, oct = lane >> 4;

    f4 acc[4][4];
#pragma unroll
    for (int i=0;i<4;++i)
#pragma unroll
        for (int j=0;j<4;++j) acc[i][j] = f4zero();

    size_t aoff[4], boff[4];
#pragma unroll
    for (int c=0;c<4;++c){
        int slot = c*256 + tid;
        int row = slot & 127, ch = slot >> 7;
        aoff[c] = (size_t)(gm0 + row)*INDIM + ch*8;
        boff[c] = (size_t)(gn0 + row)*INDIM + ch*8;
    }

#pragma unroll
    for (int c=0;c<4;++c){
        __builtin_amdgcn_global_load_lds((const AS1 U32*)(A + aoff[c]),
            (AS3 U32*)(Ab[0] + (c*256+tid)*8), 16, 0, 0);
        __builtin_amdgcn_global_load_lds((const AS1 U32*)(Bw + boff[c]),
            (AS3 U32*)(Bb[0] + (c*256+tid)*8), 16, 0, 0);
    }

#pragma unroll
    for (int kt=0; kt<6; ++kt){
        const int cur = kt & 1;
        if (kt+1 < 6){
            const int kb = (kt+1)*64;
#pragma unroll
            for (int c=0;c<4;++c){
                __builtin_amdgcn_global_load_lds((const AS1 U32*)(A + aoff[c] + kb),
                    (AS3 U32*)(Ab[cur^1] + (c*256+tid)*8), 16, 0, 0);
                __builtin_amdgcn_global_load_lds((const AS1 U32*)(Bw + boff[c] + kb),
                    (AS3 U32*)(Bb[cur^1] + (c*256+tid)*8), 16, 0, 0);
            }
            asm volatile("s_waitcnt vmcnt(8)" ::: "memory");
        } else {
            asm volatile("s_waitcnt vmcnt(0)" ::: "memory");
        }
        __builtin_amdgcn_sched_barrier(0);
        __builtin_amdgcn_s_barrier();
        __builtin_amdgcn_sched_barrier(0);

#pragma unroll
        for (int kk=0;kk<2;++kk){
            bf8 af[4], bfr[4];
#pragma unroll
            for (int i=0;i<4;++i)
                af[i]  = *(const bf8*)(Ab[cur] + ((kk*4+oct)*128 + wm*64 + i*16 + l15)*8);
#pragma unroll
            for (int j=0;j<4;++j)
                bfr[j] = *(const bf8*)(Bb[cur] + ((kk*4+oct)*128 + wn*64 + j*16 + l15)*8);
            __builtin_amdgcn_s_setprio(1);
#pragma unroll
            for (int i=0;i<4;++i)
#pragma unroll
                for (int j=0;j<4;++j)
                    acc[i][j] = __builtin_amdgcn_mfma_f32_16x16x32_bf16(af[i], bfr[j], acc[i][j], 0, 0, 0);
            __builtin_amdgcn_s_setprio(0);
        }
        __builtin_amdgcn_sched_barrier(0);
        __builtin_amdgcn_s_barrier();
        __builtin_amdgcn_sched_barrier(0);
    }

#pragma unroll
    for (int j=0;j<4;++j){
        const int col = gn0 + wn*64 + j*16 + l15;
        const float sc = s_arr[col];
        const float bi = b_arr[col];
#pragma unroll
        for (int i=0;i<4;++i){
            const int row0 = gm0 + wm*64 + i*16 + oct*4;
#pragma unroll
            for (int r=0;r<4;++r)
                o16[(size_t)(row0+r)*INDIM + col] = f2bf(acc[i][j][r]*sc + bi);
        }
    }
}

// ---------------- proj GEMM 128x128x64, counted-vmcnt double buffer ----------------
__global__ __launch_bounds__(256,2) void k_proj(
    const U16* __restrict__ A, const U16* __restrict__ Bw,
    const float* __restrict__ s_arr, const float* __restrict__ b_arr,
    float* __restrict__ o32)
{
    __shared__ U16 smem[32768];
    U16* Ab[2] = { smem,          smem + 8192 };
    U16* Bb[2] = { smem + 16384,  smem + 24576 };
    const int l   = (blockIdx.x & 7)*49 + (blockIdx.x >> 3);   // bijective (392 = 8*49)
    const int gn0 = (l & 3) * 128;
    const int gm0 = (l >> 2) * 128;
    const int tid  = threadIdx.x;
    const int lane = tid & 63;
    const int w    = tid >> 6;
    const int wm   = w >> 1, wn = w & 1;
    const int l15  = lane & 15, oct = lane >> 4;

    f4 acc[4][4];
#pragma unroll
    for (int i=0;i<4;++i)
#pragma unroll
        for (int j=0;j<4;++j) acc[i][j] = f4zero();

    size_t aoff[4], boff[4];
#pragma unroll
    for (int c=0;c<4;++c){
        int slot = c*256 + tid;
        int row = slot & 127, ch = slot >> 7;
        aoff[c] = (size_t)(gm0 + row)*DHD + ch*8;
        boff[c] = (size_t)(gn0 + row)*DHD + ch*8;
    }

#pragma unroll
    for (int c=0;c<4;++c){
        __builtin_amdgcn_global_load_lds((const AS1 U32*)(A + aoff[c]),
            (AS3 U32*)(Ab[0] + (c*256+tid)*8), 16, 0, 0);
        __builtin_amdgcn_global_load_lds((const AS1 U32*)(Bw + boff[c]),
            (AS3 U32*)(Bb[0] + (c*256+tid)*8), 16, 0, 0);
    }

#pragma unroll
    for (int kt=0; kt<12; ++kt){
        const int cur = kt & 1;
        if (kt+1 < 12){
            const int kb = (kt+1)*64;
#pragma unroll
            for (int c=0;c<4;++c){
                __builtin_amdgcn_global_load_lds((const AS1 U32*)(A + aoff[c] + kb),
                    (AS3 U32*)(Ab[cur^1] + (c*256+tid)*8), 16, 0, 0);
                __builtin_amdgcn_global_load_lds((const AS1 U32*)(Bw + boff[c] + kb),
                    (AS3 U32*)(Bb[cur^1] + (c*256+tid)*8), 16, 0, 0);
            }
            asm volatile("s_waitcnt vmcnt(8)" ::: "memory");
        } else {
            asm volatile("s_waitcnt vmcnt(0)" ::: "memory");
        }
        __builtin_amdgcn_sched_barrier(0);
        __builtin_amdgcn_s_barrier();
        __builtin_amdgcn_sched_barrier(0);

#pragma unroll
        for (int kk=0;kk<2;++kk){
            bf8 af[4], bfr[4];
#pragma unroll
            for (int i=0;i<4;++i)
                af[i]  = *(const bf8*)(Ab[cur] + ((kk*4+oct)*128 + wm*64 + i*16 + l15)*8);
#pragma unroll
            for (int j=0;j<4;++j)
                bfr[j] = *(const bf8*)(Bb[cur] + ((kk*4+oct)*128 + wn*64 + j*16 + l15)*8);
            __builtin_amdgcn_s_setprio(1);
#pragma unroll
            for (int i=0;i<4;++i)
#pragma unroll
                for (int j=0;j<4;++j)
                    acc[i][j] = __builtin_amdgcn_mfma_f32_16x16x32_bf16(af[i], bfr[j], acc[i][j], 0, 0, 0);
            __builtin_amdgcn_s_setprio(0);
        }
        __builtin_amdgcn_sched_barrier(0);
        __builtin_amdgcn_s_barrier();
        __builtin_amdgcn_sched_barrier(0);
    }

#pragma unroll
    for (int j=0;j<4;++j){
        const int col = gn0 + wn*64 + j*16 + l15;
        const float sc = s_arr[col];
        const float bi = b_arr[col];
#pragma unroll
        for (int i=0;i<4;++i){
            const int row0 = gm0 + wm*64 + i*16 + oct*4;
#pragma unroll
            for (int r=0;r<4;++r)
                o32[(size_t)(row0+r)*OUTD + col] = acc[i][j][r]*sc + bi;
        }
    }
}

// ---------------- launch ----------------
extern "C" void kernel_launch(void* const* d_in, const int* in_sizes, int n_in,
                              void* d_out, int out_size, void* d_ws, size_t ws_size,
                              hipStream_t stream)
{
    const float* x    = (const float*)d_in[0];
    const float* kv_w = (const float*)d_in[1];
    const float* kv_g = (const float*)d_in[2];
    const float* kv_b = (const float*)d_in[3];
    const float* kv_m = (const float*)d_in[4];
    const float* kv_v = (const float*)d_in[5];
    const float* q_w  = (const float*)d_in[6];
    const float* q_g  = (const float*)d_in[7];
    const float* q_b  = (const float*)d_in[8];
    const float* q_m  = (const float*)d_in[9];
    const float* q_v  = (const float*)d_in[10];
    const float* pr_w = (const float*)d_in[11];
    const float* pr_g = (const float*)d_in[12];
    const float* pr_b = (const float*)d_in[13];
    const float* pr_m = (const float*)d_in[14];
    const float* pr_v = (const float*)d_in[15];
    const float* ab   = (const float*)d_in[16];
    const int*  idxs  = (const int*)d_in[17];
    const int n_off = in_sizes[16] / NH;

    char* ws = (char*)d_ws;
    size_t off = 0;
    auto alloc = [&](size_t bytes)->char*{
        char* p = ws + off; off += (bytes + 255) & ~(size_t)255; return p;
    };
    U16*   x_bf   = (U16*)  alloc((size_t)BSZ*NPADR*INDIM*2); // 44 MB (padded)
    U16*   xs_bf  = (U16*)  alloc((size_t)BSZ*NQ*INDIM*2);    // 9.6 MB
    U16*   kvw_bf = (U16*)  alloc((size_t)KVH*INDIM*2);
    U16*   qw_bf  = (U16*)  alloc((size_t)INDIM*INDIM*2);
    U16*   prw_bf = (U16*)  alloc((size_t)OUTD*DHD*2);
    float* s_kv   = (float*)alloc(KVH*4);
    float* b_kv   = (float*)alloc(KVH*4);
    float* s_q    = (float*)alloc(INDIM*4);
    float* b_q    = (float*)alloc(INDIM*4);
    float* s_pr   = (float*)alloc(OUTD*4);
    float* b_pr   = (float*)alloc(OUTD*4);
    float* biasf  = (float*)alloc(((size_t)NH*NQ*NTOK + 256)*4);  // +pad for f4 tail reads
    U16*   q_out  = (U16*)  alloc((size_t)BSZ*NQ*INDIM*2);    // 9.6 MB
    U16*   a_out  = (U16*)  alloc((size_t)BSZ*NQ*DHD*2);      // 19.3 MB
    if (off > ws_size) return;  // insufficient workspace: fail visibly (no OOB writes)

    // prep (4 launches)
    {
        int n8 = BSZ*NPADR*INDIM/8;
        k_cast8p<<<(n8+255)/256, 256, 0, stream>>>(x, x_bf, n8);
    }
    {
        int n8 = BSZ*NQ*INDIM/8;
        k_castxs<<<(n8+255)/256, 256, 0, stream>>>(x, xs_bf, n8);
    }
    k_castw<<<(W1C+W2C+W3C+255)/256, 256, 0, stream>>>(kv_w, q_w, pr_w, kvw_bf, qw_bf, prw_bf);
    k_misc<<<BIAS_BLK+BN_BLK, 256, 0, stream>>>(
        ab, idxs, n_off,
        kv_g, kv_b, kv_m, kv_v, q_g, q_b, q_m, q_v, pr_g, pr_b, pr_m, pr_v,
        s_kv, b_kv, s_q, b_q, s_pr, b_pr, biasf);

    // q GEMM: (12544 x 384 x 384) -> bf16 row-major
    {
        dim3 g(INDIM/128, BSZ*NQ/128);
        k_qgemm<<<g, 256, 0, stream>>>(xs_bf, qw_bf, s_q, b_q, q_out);
    }
    // fused kv-GEMM + attention + hard_swish (1 head/block, 4 blocks/CU, XCD-swizzled)
    k_fused<<<BSZ*NH, 256, 0, stream>>>(x_bf, kvw_bf, q_out, s_kv, b_kv, biasf, a_out);
    // proj GEMM: (12544 x 512 x 768) -> f32 out (XCD-swizzled 1-D grid)
    k_proj<<<392, 256, 0, stream>>>(a_out, prw_bf, s_pr, b_pr, (float*)d_out);
}

// Round 11
// 191.253 us; speedup vs baseline: 1.8058x; 1.8058x over previous
//
#include <hip/hip_runtime.h>
#include <hip/hip_bf16.h>
#include <math.h>

typedef unsigned short U16;
typedef unsigned int U32;
typedef __attribute__((ext_vector_type(8))) short bf8;        // 8 x bf16 (MFMA A/B frag)
typedef __attribute__((ext_vector_type(4))) float f4;         // MFMA C/D frag
typedef __attribute__((ext_vector_type(4))) unsigned short u16x4;

#define AS1 __attribute__((address_space(1)))
#define AS3 __attribute__((address_space(3)))

// ---- constants ----
#define BSZ   256
#define NTOK  196
#define NQ    49
#define INDIM 384
#define OUTD  512
#define NH    12
#define DV    64
#define DHD   768
#define KVH   1152
#define NPADR 224      // padded token rows (196 real + 28 zero)

__device__ inline U16 f2bf(float f){
    __hip_bfloat16 h = __float2bfloat16(f);
    return *(U16*)&h;
}
__device__ inline f4 f4zero(){ f4 z; z[0]=0.f; z[1]=0.f; z[2]=0.f; z[3]=0.f; return z; }
__device__ inline bf8 bf8zero(){ bf8 v;
#pragma unroll
    for (int j=0;j<8;++j) v[j]=0; return v; }

// ---------------- prep kernels ----------------
// cast x -> x_bf padded [256][224][384] (rows 196..223 = 0)
__global__ void k_cast8p(const float* __restrict__ in, U16* __restrict__ out, int n8){
    int i = blockIdx.x*256 + threadIdx.x;
    if (i >= n8) return;
    int rall = i / 48;         // 48 = 384/8
    int c8   = i - rall*48;
    int b    = rall / NPADR;
    int r    = rall - b*NPADR;
    U16 o[8];
    if (r < NTOK){
        const float* p = in + ((size_t)(b*NTOK + r))*INDIM + c8*8;
#pragma unroll
        for (int j=0;j<8;++j) o[j] = f2bf(p[j]);
    } else {
#pragma unroll
        for (int j=0;j<8;++j) o[j] = 0;
    }
    *(bf8*)(out + (size_t)i*8) = *(const bf8*)o;
}

// subsampled xs cast: [256][49][384]
__global__ void k_castxs(const float* __restrict__ x, U16* __restrict__ out, int n8){
    int i = blockIdx.x*256 + threadIdx.x;
    if (i >= n8) return;
    int row = i / 48;
    int c8  = i - row*48;
    int b   = row / 49;
    int q   = row - b*49;
    int r_  = q / 7, c_ = q - r_*7;
    const float* p = x + ((size_t)(b*NTOK + 28*r_ + 2*c_))*INDIM + c8*8;
    U16 o[8];
#pragma unroll
    for (int j=0;j<8;++j) o[j] = f2bf(p[j]);
    *(bf8*)(out + (size_t)i*8) = *(const bf8*)o;
}

// all three weight casts in one launch
#define W1C (KVH*INDIM/8)            // 55296
#define W2C (INDIM*INDIM/8)          // 18432
#define W3C (OUTD*DHD/8)             // 49152
__global__ void k_castw(const float* __restrict__ w1, const float* __restrict__ w2,
                        const float* __restrict__ w3, U16* __restrict__ o1,
                        U16* __restrict__ o2, U16* __restrict__ o3){
    int i = blockIdx.x*256 + threadIdx.x;
    const float* p; U16* o;
    if (i < W1C){ p = w1 + (size_t)i*8; o = o1 + (size_t)i*8; }
    else if (i < W1C+W2C){ int k=i-W1C; p = w2 + (size_t)k*8; o = o2 + (size_t)k*8; }
    else if (i < W1C+W2C+W3C){ int k=i-W1C-W2C; p = w3 + (size_t)k*8; o = o3 + (size_t)k*8; }
    else return;
    U16 t[8];
#pragma unroll
    for (int j=0;j<8;++j) t[j] = f2bf(p[j]);
    *(bf8*)o = *(const bf8*)t;
}

// bias expand + BN folds, one launch
#define BIAS_N   (NH*NQ*NTOK)        // 115248
#define BIAS_BLK ((BIAS_N+255)/256)  // 451
#define BN_BLK   ((KVH+INDIM+OUTD)/256)  // 8
__global__ void k_misc(const float* __restrict__ ab, const int* __restrict__ idxs, int n_off,
                       const float* __restrict__ g1, const float* __restrict__ b1,
                       const float* __restrict__ m1, const float* __restrict__ v1,
                       const float* __restrict__ g2, const float* __restrict__ b2,
                       const float* __restrict__ m2, const float* __restrict__ v2,
                       const float* __restrict__ g3, const float* __restrict__ b3,
                       const float* __restrict__ m3, const float* __restrict__ v3,
                       float* __restrict__ s1, float* __restrict__ bo1,
                       float* __restrict__ s2, float* __restrict__ bo2,
                       float* __restrict__ s3, float* __restrict__ bo3,
                       float* __restrict__ bias_out){
    int blk = blockIdx.x;
    int tid = threadIdx.x;
    if (blk < BIAS_BLK){
        int i = blk*256 + tid;
        if (i < BIAS_N){
            int h = i / (NQ*NTOK);
            int qk = i - h*(NQ*NTOK);
            bias_out[i] = ab[h*n_off + idxs[qk]];
        }
    } else {
        int i = (blk-BIAS_BLK)*256 + tid;
        const float *g,*b,*m,*v; float *so,*bo; int k;
        if (i < KVH){ g=g1;b=b1;m=m1;v=v1;so=s1;bo=bo1;k=i; }
        else if (i < KVH+INDIM){ g=g2;b=b2;m=m2;v=v2;so=s2;bo=bo2;k=i-KVH; }
        else { g=g3;b=b3;m=m3;v=v3;so=s3;bo=bo3;k=i-KVH-INDIM; }
        float s = g[k] / sqrtf(v[k] + 1e-5f);
        so[k] = s;
        bo[k] = b[k] - m[k]*s;
    }
}

// ---------------- fused kv-GEMM + attention: 1 head/block, target 4 blocks/CU ----------------
// GEMM: C[224 rows][96 cols = k(32)|v(64)], BK=32, 12 K-steps, uniform 5 loads/thr/step,
// counted vmcnt(5). LDS = 20480 u16 = 40,960 B -> 4 blocks/CU by LDS (needs VGPR <= 128).
//   staging: A0 [0,7168) A1 [7168,14336) B0 [14336,17408) B1 [17408,20480)
//   post-GEMM (aliases dead staging):
//     VL [0,12800):      [nch<=24][64 d][8 nsub] (writes guarded n0<200)
//     KL [12800,19968):  [4 dch][224 n][8 dsub]
//     PV reads VL nch 25..27 (n>=200) overlap KL -> finite garbage x P=0 = 0.
// P never hits LDS: cross-lane __shfl transpose into PV A-frags (packed on the fly).
#define KLO 12800
__global__ __launch_bounds__(256,2) void k_fused(
    const U16* __restrict__ xbf, const U16* __restrict__ kvw, const U16* __restrict__ qo_,
    const float* __restrict__ skv, const float* __restrict__ bkv,
    const float* __restrict__ biasf, U16* __restrict__ aout)
{
    __shared__ U16 smem[20480];   // 40,960 B
    const int hw = blockIdx.x;
    const int bh = (hw & 7)*384 + (hw >> 3);   // bijective XCD swizzle (3072 = 8*384)
    const int b = bh / NH, h = bh - b*NH;
    const int tid = threadIdx.x, lane = tid & 63, w = tid >> 6;
    const int wm = w & 1, wn = w >> 1;
    const int l15 = lane & 15, oct = lane >> 4;

    U16* Ab[2] = { smem + 0,     smem + 7168 };
    U16* Bb[2] = { smem + 14336, smem + 17408 };

    // A: 896 chunks (slot = kch*224 + row); threads 0..127 take a 4th
    U32 aoff[4];
#pragma unroll
    for (int c=0;c<3;++c){
        int s = c*256 + tid;
        int ach = s / NPADR, ar = s - ach*NPADR;
        aoff[c] = (U32)(b*NPADR + ar)*INDIM + ach*8;
    }
    {
        int s = 768 + (tid & 127);
        int ach = s / NPADR, ar = s - ach*NPADR;
        aoff[3] = (U32)(b*NPADR + ar)*INDIM + ach*8;
    }
    // B: 384 chunks (slot = kch*96 + row); threads >=128 take a 2nd
    U32 boff[2];
    {
        int s0 = tid;
        int bc0 = s0 / 96, br0 = s0 - bc0*96;
        boff[0] = (U32)(h*96 + br0)*INDIM + bc0*8;
        int s1 = 128 + (tid | 128);            // tid>=128 -> 256..383
        int bc1 = s1 / 96, br1 = s1 - bc1*96;
        boff[1] = (U32)(h*96 + br1)*INDIM + bc1*8;
    }

    f4 acc[7][3];
#pragma unroll
    for (int i=0;i<7;++i)
#pragma unroll
        for (int j=0;j<3;++j) acc[i][j] = f4zero();

#define STAGE(buf, kb) do{ \
    _Pragma("unroll") \
    for (int c=0;c<3;++c) \
        __builtin_amdgcn_global_load_lds((const AS1 U32*)(xbf + aoff[c] + (kb)), \
            (AS3 U32*)(Ab[buf] + (c*256+tid)*8), 16, 0, 0); \
    if (tid < 128) \
        __builtin_amdgcn_global_load_lds((const AS1 U32*)(xbf + aoff[3] + (kb)), \
            (AS3 U32*)(Ab[buf] + (768+tid)*8), 16, 0, 0); \
    __builtin_amdgcn_global_load_lds((const AS1 U32*)(kvw + boff[0] + (kb)), \
        (AS3 U32*)(Bb[buf] + tid*8), 16, 0, 0); \
    if (tid >= 128) \
        __builtin_amdgcn_global_load_lds((const AS1 U32*)(kvw + boff[1] + (kb)), \
            (AS3 U32*)(Bb[buf] + (128+tid)*8), 16, 0, 0); \
}while(0)

    STAGE(0, 0);

#pragma unroll
    for (int kt=0; kt<12; ++kt){
        const int cur = kt & 1;
        if (kt < 11){
            STAGE(cur^1, (kt+1)*32);
            asm volatile("s_waitcnt vmcnt(5)" ::: "memory");   // tile kt landed; kt+1 in flight
        } else {
            asm volatile("s_waitcnt vmcnt(0)" ::: "memory");
        }
        __builtin_amdgcn_sched_barrier(0);
        __builtin_amdgcn_s_barrier();
        __builtin_amdgcn_sched_barrier(0);

        bf8 af[7], bfr[3];
#pragma unroll
        for (int i=0;i<7;++i)
            af[i]  = *(const bf8*)(Ab[cur] + (oct*NPADR + wm*112 + i*16 + l15)*8);
#pragma unroll
        for (int j=0;j<3;++j)
            bfr[j] = *(const bf8*)(Bb[cur] + (oct*96 + wn*48 + j*16 + l15)*8);
        __builtin_amdgcn_s_setprio(1);
#pragma unroll
        for (int i=0;i<7;++i)
#pragma unroll
            for (int j=0;j<3;++j)
                acc[i][j] = __builtin_amdgcn_mfma_f32_16x16x32_bf16(af[i], bfr[j], acc[i][j], 0, 0, 0);
        __builtin_amdgcn_s_setprio(0);
        __builtin_amdgcn_sched_barrier(0);
        __builtin_amdgcn_s_barrier();       // buf `cur` free for next iteration's staging
        __builtin_amdgcn_sched_barrier(0);
    }
#undef STAGE

    // ---- epilogue: BN fold, scatter acc -> VL/KL (alias dead staging) ----
#pragma unroll
    for (int j=0;j<3;++j){
        const int cc = wn*48 + j*16 + l15;     // [0,96)
        const float sc = skv[h*96 + cc];
        const float bi = bkv[h*96 + cc];
#pragma unroll
        for (int i=0;i<7;++i){
            const int n0 = wm*112 + i*16 + oct*4;  // [0,224)
            if (cc < 32){
#pragma unroll
                for (int r=0;r<4;++r)
                    smem[KLO + ((cc>>3)*NPADR + n0 + r)*8 + (cc&7)] = f2bf(acc[i][j][r]*sc + bi);
            } else if (n0 < 200){              // protect KL overlap (nch>=25 unused: P=0)
                const int dv = cc - 32;
                u16x4 pk;
#pragma unroll
                for (int r=0;r<4;++r) pk[r] = f2bf(acc[i][j][r]*sc + bi);
                *(u16x4*)(smem + ((n0>>3)*64 + dv)*8 + (oct&1)*4) = pk;
            }
        }
    }
    __syncthreads();   // K/V visible to all waves

    // ---- attention: 4 waves, each wave 16 q-cols ----
    const int qg = w*16 + l15;
    bf8 qf = bf8zero();
    if (qg < NQ) qf = *(const bf8*)(qo_ + ((size_t)(b*NQ + qg))*INDIM + h*32 + oct*8);

    f4 sacc[14];
#pragma unroll
    for (int mt=0;mt<14;++mt) sacc[mt] = f4zero();
#pragma unroll
    for (int mt=0;mt<14;++mt){
        const bf8 kf = *(const bf8*)(smem + KLO + (oct*NPADR + mt*16 + l15)*8);
        sacc[mt] = __builtin_amdgcn_mfma_f32_16x16x32_bf16(kf, qf, sacc[mt], 0, 0, 0);
    }

    const float scale = 0.17677669529663689f;   // 1/sqrt(32)
    float mx = -1e30f;
#pragma unroll
    for (int mt=0;mt<14;++mt){
        const int n0 = mt*16 + oct*4;
        f4 bi4 = f4zero();
        if (qg < NQ && n0 < NTOK) bi4 = *(const f4*)(biasf + ((size_t)h*NQ + qg)*NTOK + n0);
#pragma unroll
        for (int r=0;r<4;++r){
            float s = (n0 + r < NTOK) ? sacc[mt][r]*scale + bi4[r] : -1e30f;
            sacc[mt][r] = s;
            mx = fmaxf(mx, s);
        }
    }
    mx = fmaxf(mx, __shfl_xor(mx, 16));
    mx = fmaxf(mx, __shfl_xor(mx, 32));

    float sum = 0.f;
#pragma unroll
    for (int mt=0;mt<14;++mt){
#pragma unroll
        for (int r=0;r<4;++r){
            float p = (mt*16 + oct*4 + r < NTOK) ? __expf(sacc[mt][r] - mx) : 0.f;
            sacc[mt][r] = p;
            sum += p;
        }
    }
    sum += __shfl_xor(sum, 16);
    sum += __shfl_xor(sum, 32);
    const float inv = 1.f / sum;

    // PV: out(q,d) = P(q,n) @ v(n,d); A-frag via cross-lane shfl transpose.
    // P packed to bf16-pair words on the fly per kt (keeps register peak low).
    const int src1 = l15 + (oct & 1)*32;   // source lane for j0..3
    const int src2 = src1 + 16;            // source lane for j4..7
    const bool hiT = (oct >> 1) != 0;      // tile select: mt = 2kt + (oct>>1)
    f4 pacc[4];
#pragma unroll
    for (int dt=0;dt<4;++dt) pacc[dt] = f4zero();
#pragma unroll
    for (int kt=0;kt<7;++kt){
        const int m0 = 2*kt, m1 = 2*kt+1;
        U32 q00 = (U32)f2bf(sacc[m0][0]*inv) | ((U32)f2bf(sacc[m0][1]*inv) << 16);
        U32 q01 = (U32)f2bf(sacc[m0][2]*inv) | ((U32)f2bf(sacc[m0][3]*inv) << 16);
        U32 q10 = (U32)f2bf(sacc[m1][0]*inv) | ((U32)f2bf(sacc[m1][1]*inv) << 16);
        U32 q11 = (U32)f2bf(sacc[m1][2]*inv) | ((U32)f2bf(sacc[m1][3]*inv) << 16);
        U32 a0 = __shfl(q00, src1), a1 = __shfl(q01, src1);
        U32 c0 = __shfl(q10, src1), c1 = __shfl(q11, src1);
        U32 b0 = __shfl(q00, src2), b1 = __shfl(q01, src2);
        U32 d0 = __shfl(q10, src2), d1 = __shfl(q11, src2);
        union { U32 u[4]; bf8 v; } pu;
        pu.u[0] = hiT ? c0 : a0;
        pu.u[1] = hiT ? c1 : a1;
        pu.u[2] = hiT ? d0 : b0;
        pu.u[3] = hiT ? d1 : b1;
#pragma unroll
        for (int dt=0;dt<4;++dt){
            const bf8 vf = *(const bf8*)(smem + ((kt*4 + oct)*64 + dt*16 + l15)*8);
            pacc[dt] = __builtin_amdgcn_mfma_f32_16x16x32_bf16(pu.v, vf, pacc[dt], 0, 0, 0);
        }
    }

    // hard_swish, store bf16 (b, q, h*64+d)
#pragma unroll
    for (int dt=0;dt<4;++dt){
#pragma unroll
        for (int r=0;r<4;++r){
            const int qo2 = w*16 + oct*4 + r;
            if (qo2 < NQ){
                const int d = dt*16 + l15;
                float v = pacc[dt][r];
                float tt = fminf(fmaxf(v + 3.f, 0.f), 6.f);
                aout[((size_t)(b*NQ + qo2))*DHD + h*DV + d] = f2bf(v * tt * (1.f/6.f));
            }
        }
    }
}

// ---------------- q GEMM 128x128x64 (12544 x 384 x 384), bf16 out ----------------
__global__ __launch_bounds__(256,2) void k_qgemm(
    const U16* __restrict__ A, const U16* __restrict__ Bw,
    const float* __restrict__ s_arr, const float* __restrict__ b_arr,
    U16* __restrict__ o16)
{
    __shared__ U16 smem[32768];
    U16* Ab[2] = { smem,          smem + 8192 };
    U16* Bb[2] = { smem + 16384,  smem + 24576 };
    const int gn0 = blockIdx.x * 128;
    const int gm0 = blockIdx.y * 128;
    const int tid  = threadIdx.x;
    const int lane = tid & 63;
    const int w    = tid >> 6;
    const int wm   = w >> 1, wn = w & 1;
    const int l15  = lane & 15, oct = lane >> 4;

    f4 acc[4][4];
#pragma unroll
    for (int i=0;i<4;++i)
#pragma unroll
        for (int j=0;j<4;++j) acc[i][j] = f4zero();

    size_t aoff[4], boff[4];
#pragma unroll
    for (int c=0;c<4;++c){
        int slot = c*256 + tid;
        int row = slot & 127, ch = slot >> 7;
        aoff[c] = (size_t)(gm0 + row)*INDIM + ch*8;
        boff[c] = (size_t)(gn0 + row)*INDIM + ch*8;
    }

#pragma unroll
    for (int c=0;c<4;++c){
        __builtin_amdgcn_global_load_lds((const AS1 U32*)(A + aoff[c]),
            (AS3 U32*)(Ab[0] + (c*256+tid)*8), 16, 0, 0);
        __builtin_amdgcn_global_load_lds((const AS1 U32*)(Bw + boff[c]),
            (AS3 U32*)(Bb[0] + (c*256+tid)*8), 16, 0, 0);
    }

#pragma unroll
    for (int kt=0; kt<6; ++kt){
        const int cur = kt & 1;
        if (kt+1 < 6){
            const int kb = (kt+1)*64;
#pragma unroll
            for (int c=0;c<4;++c){
                __builtin_amdgcn_global_load_lds((const AS1 U32*)(A + aoff[c] + kb),
                    (AS3 U32*)(Ab[cur^1] + (c*256+tid)*8), 16, 0, 0);
                __builtin_amdgcn_global_load_lds((const AS1 U32*)(Bw + boff[c] + kb),
                    (AS3 U32*)(Bb[cur^1] + (c*256+tid)*8), 16, 0, 0);
            }
            asm volatile("s_waitcnt vmcnt(8)" ::: "memory");
        } else {
            asm volatile("s_waitcnt vmcnt(0)" ::: "memory");
        }
        __builtin_amdgcn_sched_barrier(0);
        __builtin_amdgcn_s_barrier();
        __builtin_amdgcn_sched_barrier(0);

#pragma unroll
        for (int kk=0;kk<2;++kk){
            bf8 af[4], bfr[4];
#pragma unroll
            for (int i=0;i<4;++i)
                af[i]  = *(const bf8*)(Ab[cur] + ((kk*4+oct)*128 + wm*64 + i*16 + l15)*8);
#pragma unroll
            for (int j=0;j<4;++j)
                bfr[j] = *(const bf8*)(Bb[cur] + ((kk*4+oct)*128 + wn*64 + j*16 + l15)*8);
            __builtin_amdgcn_s_setprio(1);
#pragma unroll
            for (int i=0;i<4;++i)
#pragma unroll
                for (int j=0;j<4;++j)
                    acc[i][j] = __builtin_amdgcn_mfma_f32_16x16x32_bf16(af[i], bfr[j], acc[i][j], 0, 0, 0);
            __builtin_amdgcn_s_setprio(0);
        }
        __builtin_amdgcn_sched_barrier(0);
        __builtin_amdgcn_s_barrier();
        __builtin_amdgcn_sched_barrier(0);
    }

#pragma unroll
    for (int j=0;j<4;++j){
        const int col = gn0 + wn*64 + j*16 + l15;
        const float sc = s_arr[col];
        const float bi = b_arr[col];
#pragma unroll
        for (int i=0;i<4;++i){
            const int row0 = gm0 + wm*64 + i*16 + oct*4;
#pragma unroll
            for (int r=0;r<4;++r)
                o16[(size_t)(row0+r)*INDIM + col] = f2bf(acc[i][j][r]*sc + bi);
        }
    }
}

// ---------------- proj GEMM 128x128x64, counted-vmcnt double buffer ----------------
__global__ __launch_bounds__(256,2) void k_proj(
    const U16* __restrict__ A, const U16* __restrict__ Bw,
    const float* __restrict__ s_arr, const float* __restrict__ b_arr,
    float* __restrict__ o32)
{
    __shared__ U16 smem[32768];
    U16* Ab[2] = { smem,          smem + 8192 };
    U16* Bb[2] = { smem + 16384,  smem + 24576 };
    const int l   = (blockIdx.x & 7)*49 + (blockIdx.x >> 3);   // bijective (392 = 8*49)
    const int gn0 = (l & 3) * 128;
    const int gm0 = (l >> 2) * 128;
    const int tid  = threadIdx.x;
    const int lane = tid & 63;
    const int w    = tid >> 6;
    const int wm   = w >> 1, wn = w & 1;
    const int l15  = lane & 15, oct = lane >> 4;

    f4 acc[4][4];
#pragma unroll
    for (int i=0;i<4;++i)
#pragma unroll
        for (int j=0;j<4;++j) acc[i][j] = f4zero();

    size_t aoff[4], boff[4];
#pragma unroll
    for (int c=0;c<4;++c){
        int slot = c*256 + tid;
        int row = slot & 127, ch = slot >> 7;
        aoff[c] = (size_t)(gm0 + row)*DHD + ch*8;
        boff[c] = (size_t)(gn0 + row)*DHD + ch*8;
    }

#pragma unroll
    for (int c=0;c<4;++c){
        __builtin_amdgcn_global_load_lds((const AS1 U32*)(A + aoff[c]),
            (AS3 U32*)(Ab[0] + (c*256+tid)*8), 16, 0, 0);
        __builtin_amdgcn_global_load_lds((const AS1 U32*)(Bw + boff[c]),
            (AS3 U32*)(Bb[0] + (c*256+tid)*8), 16, 0, 0);
    }

#pragma unroll
    for (int kt=0; kt<12; ++kt){
        const int cur = kt & 1;
        if (kt+1 < 12){
            const int kb = (kt+1)*64;
#pragma unroll
            for (int c=0;c<4;++c){
                __builtin_amdgcn_global_load_lds((const AS1 U32*)(A + aoff[c] + kb),
                    (AS3 U32*)(Ab[cur^1] + (c*256+tid)*8), 16, 0, 0);
                __builtin_amdgcn_global_load_lds((const AS1 U32*)(Bw + boff[c] + kb),
                    (AS3 U32*)(Bb[cur^1] + (c*256+tid)*8), 16, 0, 0);
            }
            asm volatile("s_waitcnt vmcnt(8)" ::: "memory");
        } else {
            asm volatile("s_waitcnt vmcnt(0)" ::: "memory");
        }
        __builtin_amdgcn_sched_barrier(0);
        __builtin_amdgcn_s_barrier();
        __builtin_amdgcn_sched_barrier(0);

#pragma unroll
        for (int kk=0;kk<2;++kk){
            bf8 af[4], bfr[4];
#pragma unroll
            for (int i=0;i<4;++i)
                af[i]  = *(const bf8*)(Ab[cur] + ((kk*4+oct)*128 + wm*64 + i*16 + l15)*8);
#pragma unroll
            for (int j=0;j<4;++j)
                bfr[j] = *(const bf8*)(Bb[cur] + ((kk*4+oct)*128 + wn*64 + j*16 + l15)*8);
            __builtin_amdgcn_s_setprio(1);
#pragma unroll
            for (int i=0;i<4;++i)
#pragma unroll
                for (int j=0;j<4;++j)
                    acc[i][j] = __builtin_amdgcn_mfma_f32_16x16x32_bf16(af[i], bfr[j], acc[i][j], 0, 0, 0);
            __builtin_amdgcn_s_setprio(0);
        }
        __builtin_amdgcn_sched_barrier(0);
        __builtin_amdgcn_s_barrier();
        __builtin_amdgcn_sched_barrier(0);
    }

#pragma unroll
    for (int j=0;j<4;++j){
        const int col = gn0 + wn*64 + j*16 + l15;
        const float sc = s_arr[col];
        const float bi = b_arr[col];
#pragma unroll
        for (int i=0;i<4;++i){
            const int row0 = gm0 + wm*64 + i*16 + oct*4;
#pragma unroll
            for (int r=0;r<4;++r)
                o32[(size_t)(row0+r)*OUTD + col] = acc[i][j][r]*sc + bi;
        }
    }
}

// ---------------- launch ----------------
extern "C" void kernel_launch(void* const* d_in, const int* in_sizes, int n_in,
                              void* d_out, int out_size, void* d_ws, size_t ws_size,
                              hipStream_t stream)
{
    const float* x    = (const float*)d_in[0];
    const float* kv_w = (const float*)d_in[1];
    const float* kv_g = (const float*)d_in[2];
    const float* kv_b = (const float*)d_in[3];
    const float* kv_m = (const float*)d_in[4];
    const float* kv_v = (const float*)d_in[5];
    const float* q_w  = (const float*)d_in[6];
    const float* q_g  = (const float*)d_in[7];
    const float* q_b  = (const float*)d_in[8];
    const float* q_m  = (const float*)d_in[9];
    const float* q_v  = (const float*)d_in[10];
    const float* pr_w = (const float*)d_in[11];
    const float* pr_g = (const float*)d_in[12];
    const float* pr_b = (const float*)d_in[13];
    const float* pr_m = (const float*)d_in[14];
    const float* pr_v = (const float*)d_in[15];
    const float* ab   = (const float*)d_in[16];
    const int*  idxs  = (const int*)d_in[17];
    const int n_off = in_sizes[16] / NH;

    char* ws = (char*)d_ws;
    size_t off = 0;
    auto alloc = [&](size_t bytes)->char*{
        char* p = ws + off; off += (bytes + 255) & ~(size_t)255; return p;
    };
    U16*   x_bf   = (U16*)  alloc((size_t)BSZ*NPADR*INDIM*2); // 44 MB (padded)
    U16*   xs_bf  = (U16*)  alloc((size_t)BSZ*NQ*INDIM*2);    // 9.6 MB
    U16*   kvw_bf = (U16*)  alloc((size_t)KVH*INDIM*2);
    U16*   qw_bf  = (U16*)  alloc((size_t)INDIM*INDIM*2);
    U16*   prw_bf = (U16*)  alloc((size_t)OUTD*DHD*2);
    float* s_kv   = (float*)alloc(KVH*4);
    float* b_kv   = (float*)alloc(KVH*4);
    float* s_q    = (float*)alloc(INDIM*4);
    float* b_q    = (float*)alloc(INDIM*4);
    float* s_pr   = (float*)alloc(OUTD*4);
    float* b_pr   = (float*)alloc(OUTD*4);
    float* biasf  = (float*)alloc(((size_t)NH*NQ*NTOK + 256)*4);  // +pad for f4 tail reads
    U16*   q_out  = (U16*)  alloc((size_t)BSZ*NQ*INDIM*2);    // 9.6 MB
    U16*   a_out  = (U16*)  alloc((size_t)BSZ*NQ*DHD*2);      // 19.3 MB
    if (off > ws_size) return;  // insufficient workspace: fail visibly (no OOB writes)

    // prep (4 launches)
    {
        int n8 = BSZ*NPADR*INDIM/8;
        k_cast8p<<<(n8+255)/256, 256, 0, stream>>>(x, x_bf, n8);
    }
    {
        int n8 = BSZ*NQ*INDIM/8;
        k_castxs<<<(n8+255)/256, 256, 0, stream>>>(x, xs_bf, n8);
    }
    k_castw<<<(W1C+W2C+W3C+255)/256, 256, 0, stream>>>(kv_w, q_w, pr_w, kvw_bf, qw_bf, prw_bf);
    k_misc<<<BIAS_BLK+BN_BLK, 256, 0, stream>>>(
        ab, idxs, n_off,
        kv_g, kv_b, kv_m, kv_v, q_g, q_b, q_m, q_v, pr_g, pr_b, pr_m, pr_v,
        s_kv, b_kv, s_q, b_q, s_pr, b_pr, biasf);

    // q GEMM: (12544 x 384 x 384) -> bf16 row-major
    {
        dim3 g(INDIM/128, BSZ*NQ/128);
        k_qgemm<<<g, 256, 0, stream>>>(xs_bf, qw_bf, s_q, b_q, q_out);
    }
    // fused kv-GEMM + attention + hard_swish (1 head/block, 4 blocks/CU target, XCD-swizzled)
    k_fused<<<BSZ*NH, 256, 0, stream>>>(x_bf, kvw_bf, q_out, s_kv, b_kv, biasf, a_out);
    // proj GEMM: (12544 x 512 x 768) -> f32 out (XCD-swizzled 1-D grid)
    k_proj<<<392, 256, 0, stream>>>(a_out, prw_bf, s_pr, b_pr, (float*)d_out);
}